// Round 10
// baseline (505.962 us; speedup 1.0000x reference)
//
#include <hip/hip_runtime.h>
#include <math.h>

#define B_    32
#define CIN   256
#define HID   256
#define OC    65
#define A_    9
#define H_    56
#define W_    56
#define HW    3136
#define AHW   28224
#define NBOX  64
#define M_    2048
#define CNUM  20
#define NTILE 49         // HW / 64
#define NTILES_TOT (B_ * NTILE)              // 1568

#define IOU_N ((size_t)B_ * AHW * NBOX)      // 57,802,752

// workspace byte offsets (total < 1 MB)
#define WS_W1S   0
#define WS_W2S   131072
#define WS_LOSS  172032
#define WS_PCNT  172288
#define WS_NCNT  178560
#define WS_PBUF  184832
#define WS_NBUF  586240

typedef _Float16 half8 __attribute__((ext_vector_type(8)));
typedef float f32x4  __attribute__((ext_vector_type(4)));

__device__ __forceinline__ unsigned int pkh(float a, float b) {
    _Float16 ha = (_Float16)a, hb = (_Float16)b;
    unsigned short ua = __builtin_bit_cast(unsigned short, ha);
    unsigned short ub = __builtin_bit_cast(unsigned short, hb);
    return (unsigned int)ua | ((unsigned int)ub << 16);
}

// XOR bank-swizzle for the feature-fragment LDS (halfword index): folds the
// wave bits (h[13:12]) into bank bits (h[5:4]). Applied on BOTH the staging
// writes and conv1 reads -> 8-way staging conflict becomes 2-way (free).
__device__ __forceinline__ int swz(int h) { return h ^ (((h >> 12) & 3) << 4); }

__global__ __launch_bounds__(256) void zero_kernel(int* __restrict__ cnts,
                                                   float* __restrict__ loss_ws) {
    const int i = blockIdx.x * 256 + threadIdx.x;
    if (i < 2 * NTILES_TOT) cnts[i] = 0;
    if (i < 2) loss_ws[i] = 0.f;
}

// w1s/w2s in 16x16x32 A-fragment order:
// w{1,2}s[rt*4096.. ] : [rt*8+ks][lane][e] = w[rt*16 + (lane&15)][ks*32 + (lane>>4)*8 + e]
__global__ __launch_bounds__(256) void prep_kernel(
    const float* __restrict__ w1, const float* __restrict__ w2,
    _Float16* __restrict__ w1s, _Float16* __restrict__ w2s,
    const int* __restrict__ pos_idx, const int* __restrict__ neg_idx,
    int* __restrict__ pcnt, int* __restrict__ ncnt,
    int* __restrict__ pbuf, int* __restrict__ nbuf)
{
    const int f = blockIdx.x * 256 + threadIdx.x;   // 0..65535
    {
        const int e    = f & 7;
        const int lane = (f >> 3) & 63;
        const int ks   = (f >> 9) & 7;
        const int rt   = (f >> 12) & 15;
        const int row  = rt * 16 + (lane & 15);
        const int k    = ks * 32 + (lane >> 4) * 8 + e;
        w1s[f] = (_Float16)w1[row * CIN + k];
    }
    if (f < 20480) {
        const int e    = f & 7;
        const int lane = (f >> 3) & 63;
        const int ks2  = (f >> 9) & 7;
        const int rt   = f >> 12;
        const int row  = rt * 16 + (lane & 15);
        const int k    = ks2 * 32 + (lane >> 4) * 8 + e;
        w2s[f] = (row < OC) ? (_Float16)w2[row * HID + k] : (_Float16)0.f;
    }
    if (f < 2 * M_) {
        const int m   = f & (M_ - 1);
        const int idx = (f < M_) ? pos_idx[m] : neg_idx[m];
        const int bi  = idx / AHW;
        const int rr  = idx - bi * AHW;
        const int a   = rr / HW;
        const int hw  = rr - a * HW;
        const int tile = bi * NTILE + (hw >> 6);
        const int enc  = m | (a << 11) | ((hw & 63) << 15);
        if (f < M_) {
            const int s = atomicAdd(&pcnt[tile], 1);
            if (s < 64) pbuf[tile * 64 + s] = enc;
        } else {
            const int s = atomicAdd(&ncnt[tile], 1);
            if (s < 64) nbuf[tile * 64 + s] = enc;
        }
    }
}

// Wave-independent fused kernel. Block = (batch, 64-px tile); after ONE
// staging barrier, each wave runs conv1 (16x16x32, its own 16 px) -> in-reg
// shfl repack -> conv2 -> x2/proposals/IoU with ZERO barriers (all state is
// wave-local: registers or the wave's private 8KB LDS region). Waves desync
// -> MFMA/VALU/store pipes mix instead of phase-locked bursts.
__global__ __launch_bounds__(256) void conv_iou_kernel(
    const float* __restrict__ features, const _Float16* __restrict__ w1s,
    const float* __restrict__ b1, const _Float16* __restrict__ w2s,
    const float* __restrict__ b2, const float* __restrict__ anc,
    const float* __restrict__ bboxes,
    const int* __restrict__ pcnt, const int* __restrict__ ncnt,
    const int* __restrict__ pbuf, const int* __restrict__ nbuf,
    const float* __restrict__ gt_off,
    float* __restrict__ iou_out, float* __restrict__ cls_out,
    float* __restrict__ loss_ws)
{
    __shared__ _Float16 lds_h[16384];   // 32 KB: 4 wave regions of 4096 hw
    __shared__ float boxs[5 * 64];
    __shared__ float red[8];

    float* LF = (float*)lds_h;          // wave w region = floats [w*2048, +2048)

    const int t    = threadIdx.x;
    const int lane = t & 63;
    const int w    = t >> 6;
    const int g    = lane >> 4;         // quad / k-group
    const int m16  = lane & 15;
    const int bid  = blockIdx.x;
    const int b    = bid / NTILE;
    const int p0   = (bid - b * NTILE) * 64;
    const float* fbase = features + (size_t)b * CIN * HW + p0;

    if (t < 64) {
        const float* gb = bboxes + ((size_t)b * NBOX + t) * 5;
        const float x1 = gb[0], y1 = gb[1], x2v = gb[2], y2v = gb[3];
        boxs[t] = x1; boxs[64 + t] = y1; boxs[128 + t] = x2v; boxs[192 + t] = y2v;
        boxs[256 + t] = (x2v - x1) * (y2v - y1);
    }

    // ---- staging: block-cooperative, coalesced float4 reads, swizzled LDS ----
    // target layout (hw): [(px>>4)*8 + ch>>5][ ((ch>>3)&3)*16 + (px&15) ][ch&7]
    // i.e. wave (px>>4) owns frags for its 16 pixels in 16x16x32 B order.
    const int pstage = (t & 15) * 4;
    const int kk     = (t >> 4) * 2;
#pragma unroll
    for (int hf = 0; hf < 2; ++hf) {
        float4 r0[4], r1[4];
#pragma unroll
        for (int c4 = 0; c4 < 4; ++c4) {
            const int c = hf * 4 + c4;
            r0[c4] = *(const float4*)(fbase + (size_t)(c * 32 + kk) * HW + pstage);
            r1[c4] = *(const float4*)(fbase + (size_t)(c * 32 + kk + 1) * HW + pstage);
        }
#pragma unroll
        for (int c4 = 0; c4 < 4; ++c4) {
            const int c = hf * 4 + c4;
            const float a0[4] = {r0[c4].x, r0[c4].y, r0[c4].z, r0[c4].w};
            const float a1[4] = {r1[c4].x, r1[c4].y, r1[c4].z, r1[c4].w};
#pragma unroll
            for (int e = 0; e < 4; ++e) {
                const int p = pstage + e;
                const int W = ((p >> 4) * 8 + c) * 512
                            + (((kk >> 3) & 3) * 16 + (p & 15)) * 8 + (kk & 7);
                *(unsigned int*)&lds_h[swz(W)] = pkh(a0[e], a1[e]);
            }
        }
    }
    __syncthreads();   // the ONLY pre-tail barrier

    // ---- conv1: wave's 16 px x 256 hidden; 128x mfma 16x16x32 ----
    f32x4 facc[16];
#pragma unroll
    for (int rt = 0; rt < 16; ++rt)
#pragma unroll
        for (int e = 0; e < 4; ++e) facc[rt][e] = 0.f;

#pragma unroll
    for (int ks = 0; ks < 8; ++ks) {
        const half8 bf = *(const half8*)&lds_h[swz(((w * 8 + ks) * 64 + lane) * 8)];
#pragma unroll
        for (int rt = 0; rt < 16; ++rt) {
            const half8 af = *(const half8*)(w1s + ((size_t)(rt * 8 + ks) * 64 + lane) * 8);
            facc[rt] = __builtin_amdgcn_mfma_f32_16x16x32_f16(af, bf, facc[rt], 0, 0, 0);
        }
    }

    // ---- bias + leaky relu + pack pairs (rt even/odd) for the shfl repack ----
    // facc[rt][r] = x1[hid = rt*16 + g*4 + r][px = m16]
    unsigned hvpk[8][4];
#pragma unroll
    for (int rt2 = 0; rt2 < 8; ++rt2) {
        const float4 bA = *(const float4*)(b1 + (2 * rt2) * 16 + g * 4);
        const float4 bB = *(const float4*)(b1 + (2 * rt2 + 1) * 16 + g * 4);
        const float bav[4] = {bA.x, bA.y, bA.z, bA.w};
        const float bbv[4] = {bB.x, bB.y, bB.z, bB.w};
#pragma unroll
        for (int r = 0; r < 4; ++r) {
            float va = facc[2 * rt2][r] + bav[r];
            float vb = facc[2 * rt2 + 1][r] + bbv[r];
            va = va < 0.f ? 0.01f * va : va;
            vb = vb < 0.f ? 0.01f * vb : vb;
            hvpk[rt2][r] = pkh(va, vb);   // lo = rt even (hid bit4=0), hi = rt odd
        }
    }

    // ---- conv2: B-frag built in-register via shfl (no LDS round trip) ----
    // dest lane l, elem j needs hid = ks2*32 + g*8 + j at px=m16:
    //   source lane = ((g&1)*2 + (j>>2))*16 + m16, value hvpk[ks2][j&3],
    //   half selected by g>>1.
    f32x4 c2[5];
#pragma unroll
    for (int rt = 0; rt < 5; ++rt)
#pragma unroll
        for (int e = 0; e < 4; ++e) c2[rt][e] = 0.f;

    const int src0 = (g & 1) * 32 + m16;
    const int sh   = (g >> 1) * 16;
#pragma unroll
    for (int ks2 = 0; ks2 < 8; ++ks2) {
        unsigned u[8];
#pragma unroll
        for (int j = 0; j < 8; ++j)
            u[j] = (unsigned)__shfl((int)hvpk[ks2][j & 3], (j < 4) ? src0 : src0 + 16);
        union { unsigned q[4]; half8 h; } bu;
#pragma unroll
        for (int wd = 0; wd < 4; ++wd)
            bu.q[wd] = ((u[2 * wd] >> sh) & 0xffffu) | (((u[2 * wd + 1] >> sh) & 0xffffu) << 16);
#pragma unroll
        for (int rt = 0; rt < 5; ++rt) {
            const half8 af = *(const half8*)(w2s + ((size_t)(rt * 8 + ks2) * 64 + lane) * 8);
            c2[rt] = __builtin_amdgcn_mfma_f32_16x16x32_f16(af, bu.h, c2[rt], 0, 0, 0);
        }
    }
    asm volatile("" ::: "memory");   // conv1 LDS reads precede wave-region reuse

    // ---- x2 tile in the WAVE's LDS region (floats [0,1104)) ----
    float* xw = LF + w * 2048;          // xw[pw*69 + o], pw in [0,16)
#pragma unroll
    for (int rt = 0; rt < 5; ++rt) {
#pragma unroll
        for (int r = 0; r < 4; ++r) {
            const int o2 = rt * 16 + g * 4 + r;
            if (o2 < OC) xw[m16 * 69 + o2] = c2[rt][r] + b2[o2];
        }
    }
    asm volatile("" ::: "memory");

    // ---- proposals: wave's 16 px x 9 anchors (floats [1104,1824)) ----
    float* WPw = LF + w * 2048 + 1104;
    for (int i = lane; i < A_ * 16; i += 64) {
        const int a  = i >> 4;
        const int pw = i & 15;
        const float* xr = xw + pw * 69 + 5 * a;
        const float tx = xr[1], ty = xr[2], tw = xr[3], th = xr[4];
        const int hwg = p0 + w * 16 + pw;
        const int h   = hwg / W_;
        const int wv  = hwg - h * W_;
        const float gx = (float)wv + 0.5f;
        const float gy = (float)h + 0.5f;
        const float nw = anc[2 * a]     * __expf(tw);
        const float nh = anc[2 * a + 1] * __expf(th);
        const float cx = gx + tx, cy = gy + ty;
        WPw[i]       = cx - 0.5f * nw;
        WPw[144 + i] = cy - 0.5f * nh;
        WPw[288 + i] = cx + 0.5f * nw;
        WPw[432 + i] = cy + 0.5f * nh;
        WPw[576 + i] = nw * nh;
    }
    asm volatile("" ::: "memory");

    // ---- IoU stream-out (wave-private; no barriers anywhere near) ----
    const int pr = g;
    const int j0 = m16 * 4;
    float Bx1[4], By1[4], Bx2[4], By2[4], Ba[4];
#pragma unroll
    for (int e = 0; e < 4; ++e) {
        Bx1[e] = boxs[j0 + e];       By1[e] = boxs[64 + j0 + e];
        Bx2[e] = boxs[128 + j0 + e]; By2[e] = boxs[192 + j0 + e];
        Ba[e]  = boxs[256 + j0 + e];
    }
    float* ibase = iou_out + ((size_t)b * AHW + p0) * 64;
#pragma unroll 1
    for (int a = 0; a < A_; ++a) {
        float Px1[4], Py1[4], Px2[4], Py2[4], Pa[4];
#pragma unroll
        for (int q = 0; q < 4; ++q) {
            const int idx = a * 16 + q * 4 + pr;
            Px1[q] = WPw[idx];       Py1[q] = WPw[144 + idx];
            Px2[q] = WPw[288 + idx]; Py2[q] = WPw[432 + idx];
            Pa[q]  = WPw[576 + idx];
        }
#pragma unroll
        for (int q = 0; q < 4; ++q) {
            f32x4 o4;
#pragma unroll
            for (int e = 0; e < 4; ++e) {
                const float iw = fminf(Px2[q], Bx2[e]) - fmaxf(Px1[q], Bx1[e]);
                const float ih = fminf(Py2[q], By2[e]) - fmaxf(Py1[q], By1[e]);
                const float inter = fmaxf(iw, 0.f) * fmaxf(ih, 0.f);
                o4[e] = inter * __builtin_amdgcn_rcpf(Ba[e] + Pa[q] - inter);
            }
            *(f32x4*)(ibase + ((size_t)(a * HW) + w * 16 + q * 4 + pr) * 64 + j0) = o4;
        }
    }

    // ---- LDS-only barrier (IoU stores stay in flight), then bucketed tail ----
    __builtin_amdgcn_sched_barrier(0);
    asm volatile("s_waitcnt lgkmcnt(0)" ::: "memory");
    __builtin_amdgcn_s_barrier();
    __builtin_amdgcn_sched_barrier(0);

    float csum = 0.f, rsum = 0.f;
    {
        int np = pcnt[bid]; np = np > 64 ? 64 : np;
        for (int i = t; i < np; i += 256) {
            const int e  = pbuf[bid * 64 + i];
            const int m  = e & 2047;
            const int a  = (e >> 11) & 15;
            const int px = (e >> 15) & 63;
            const float* xr = LF + (px >> 4) * 2048 + (px & 15) * 69;
            const float s = 1.f / (1.f + __expf(-xr[5 * a]));
            csum += (s - 1.f) * (s - 1.f);
#pragma unroll
            for (int k = 0; k < 4; ++k) {
                const float d = xr[5 * a + 1 + k] - gt_off[m * 4 + k];
                rsum += d * d;
            }
            float* co = cls_out + (size_t)m * CNUM;
#pragma unroll
            for (int c = 0; c < CNUM; ++c) co[c] = xr[45 + c];
        }
        int nn = ncnt[bid]; nn = nn > 64 ? 64 : nn;
        for (int i = t; i < nn; i += 256) {
            const int e  = nbuf[bid * 64 + i];
            const int a  = (e >> 11) & 15;
            const int px = (e >> 15) & 63;
            const float* xr = LF + (px >> 4) * 2048 + (px & 15) * 69;
            const float s = 1.f / (1.f + __expf(-xr[5 * a]));
            csum += s * s;
        }
    }
#pragma unroll
    for (int off = 32; off > 0; off >>= 1) {
        csum += __shfl_down(csum, off, 64);
        rsum += __shfl_down(rsum, off, 64);
    }
    if (lane == 0) { red[w] = csum; red[4 + w] = rsum; }
    __syncthreads();
    if (t == 0) {
        const float c  = red[0] + red[1] + red[2] + red[3];
        const float rg = red[4] + red[5] + red[6] + red[7];
        if (c != 0.f || rg != 0.f) {
            atomicAdd(&loss_ws[0], c);
            atomicAdd(&loss_ws[1], rg);
        }
    }
}

__global__ void finalize_kernel(const float* __restrict__ loss_ws, float* __restrict__ out0)
{
    out0[0] = loss_ws[0] / (2.f * (float)M_) + loss_ws[1] / (float)M_;
}

extern "C" void kernel_launch(void* const* d_in, const int* in_sizes, int n_in,
                              void* d_out, int out_size, void* d_ws, size_t ws_size,
                              hipStream_t stream) {
    (void)in_sizes; (void)n_in; (void)out_size; (void)ws_size;
    const float* features = (const float*)d_in[0];
    const float* w1       = (const float*)d_in[1];
    const float* b1       = (const float*)d_in[2];
    const float* w2       = (const float*)d_in[3];
    const float* b2       = (const float*)d_in[4];
    const float* anc      = (const float*)d_in[5];
    const float* bboxes   = (const float*)d_in[7];
    const float* gt_off   = (const float*)d_in[8];
    const int*   pos_idx  = (const int*)d_in[9];
    const int*   neg_idx  = (const int*)d_in[10];
    float* out = (float*)d_out;

    char* wsb = (char*)d_ws;
    _Float16* w1s  = (_Float16*)(wsb + WS_W1S);
    _Float16* w2s  = (_Float16*)(wsb + WS_W2S);
    float* loss_ws = (float*)(wsb + WS_LOSS);
    int*   pcnt    = (int*)(wsb + WS_PCNT);
    int*   ncnt    = (int*)(wsb + WS_NCNT);
    int*   pbuf    = (int*)(wsb + WS_PBUF);
    int*   nbuf    = (int*)(wsb + WS_NBUF);

    zero_kernel<<<13, 256, 0, stream>>>(pcnt, loss_ws);
    prep_kernel<<<256, 256, 0, stream>>>(w1, w2, w1s, w2s, pos_idx, neg_idx,
                                         pcnt, ncnt, pbuf, nbuf);
    conv_iou_kernel<<<NTILES_TOT, 256, 0, stream>>>(features, w1s, b1, w2s, b2,
                                                    anc, bboxes, pcnt, ncnt, pbuf, nbuf,
                                                    gt_off, out + 1,
                                                    out + 1 + IOU_N, loss_ws);
    finalize_kernel<<<1, 1, 0, stream>>>(loss_ws, out);
}

// Round 11
// 384.769 us; speedup vs baseline: 1.3150x; 1.3150x over previous
//
#include <hip/hip_runtime.h>
#include <math.h>

#define B_    32
#define CIN   256
#define HID   256
#define OC    65
#define A_    9
#define H_    56
#define W_    56
#define HW    3136
#define AHW   28224
#define NBOX  64
#define M_    2048
#define CNUM  20
#define NTILE 49         // HW / 64

#define IOU_N ((size_t)B_ * AHW * NBOX)      // 57,802,752

// padded LDS fragment offset (halfwords): +16B every 8 fragment rows.
#define FOFF(frag) (((frag) << 3) + ((((frag) >> 3)) << 3))

typedef _Float16 half8 __attribute__((ext_vector_type(8)));
typedef float f32x16 __attribute__((ext_vector_type(16)));
typedef float f32x4  __attribute__((ext_vector_type(4)));

__device__ __forceinline__ unsigned int pkh(float a, float b) {
    _Float16 ha = (_Float16)a, hb = (_Float16)b;
    unsigned short ua = __builtin_bit_cast(unsigned short, ha);
    unsigned short ub = __builtin_bit_cast(unsigned short, hb);
    return (unsigned int)ua | ((unsigned int)ub << 16);
}

// Pre-swizzle weights into MFMA A-fragment order (fp16); zero the loss accumulators.
__global__ __launch_bounds__(256) void prep_kernel(
    const float* __restrict__ w1, const float* __restrict__ w2,
    _Float16* __restrict__ w1s, _Float16* __restrict__ w2s,
    float* __restrict__ loss_ws)
{
    const int f = blockIdx.x * 256 + threadIdx.x;   // 0..65535
    if (f < 2) loss_ws[f] = 0.f;
    {
        const int e    = f & 7;
        const int lane = (f >> 3) & 63;
        const int kc   = (f >> 9) & 15;
        const int ob   = f >> 13;
        const int row  = ob * 32 + (lane & 31);
        const int k    = kc * 16 + (lane >> 5) * 8 + e;
        w1s[f] = (_Float16)w1[row * CIN + k];
    }
    if (f < 20480) {
        const int e    = f & 7;
        const int lane = (f >> 3) & 63;
        const int ks2  = (f >> 9) & 7;
        const int rt   = f >> 12;
        const int row  = rt * 16 + (lane & 15);
        const int k    = ks2 * 32 + (lane >> 4) * 8 + e;
        w2s[f] = (row < OC) ? (_Float16)w2[row * HID + k] : (_Float16)0.f;
    }
}

// Fused conv1 + conv2 + IoU + class-gather + loss-partials.
// Best-known configuration (R5: 143.5us conv, passed): 32x32x16 conv1 with
// rolling weight prefetch, batched staging loads, wave-local proposals+IoU
// (no barrier between conv2 epilogue and IoU), merged pos/neg scan tail.
__global__ __launch_bounds__(256) void conv_iou_kernel(
    const float* __restrict__ features, const _Float16* __restrict__ w1s,
    const float* __restrict__ b1, const _Float16* __restrict__ w2s,
    const float* __restrict__ b2, const float* __restrict__ anc,
    const float* __restrict__ bboxes, const int* __restrict__ pos_idx,
    const int* __restrict__ neg_idx, const float* __restrict__ gt_off,
    float* __restrict__ iou_out, float* __restrict__ cls_out,
    float* __restrict__ loss_ws)
{
    __shared__ _Float16 lds_h[18432];   // 36 KB: feat frags -> hidf -> x2t+WP
    __shared__ float bias_s[HID];       // 1 KB
    __shared__ float boxs[5 * 64];      // 1.25 KB
    __shared__ float red[8];

    _Float16* featAll = lds_h;
    _Float16* hidf    = lds_h;
    float*    L       = (float*)lds_h;
    float*    x2t     = L;              // 64*69 floats (stride-69, conflict-free)

    const int t    = threadIdx.x;
    const int lane = t & 63;
    const int w    = t >> 6;
    const int bid  = blockIdx.x;
    const int b    = bid / NTILE;
    const int p0   = (bid - b * NTILE) * 64;
    const float* fbase = features + (size_t)b * CIN * HW + p0;

    float* WPw = L + 4416 + w * 720;    // per-wave proposals: 5 planes x 144

    bias_s[t] = b1[t];
    if (t < 64) {
        const float* gb = bboxes + ((size_t)b * NBOX + t) * 5;
        const float x1 = gb[0], y1 = gb[1], x2v = gb[2], y2v = gb[3];
        boxs[t] = x1; boxs[64 + t] = y1; boxs[128 + t] = x2v; boxs[192 + t] = y2v;
        boxs[256 + t] = (x2v - x1) * (y2v - y1);
    }

    // staging coords
    const int pstage = (t & 15) * 4;
    const int kk     = (t >> 4) * 2;
    const int ksS    = kk >> 4;
    const int gS     = (kk >> 3) & 1;
    const int j0h    = kk & 7;
    const int ghalf  = lane >> 5;

    // ---- stage ALL 8 feature chunks, fp32->fp16, padded fragment order ----
#pragma unroll
    for (int hf = 0; hf < 2; ++hf) {
        float4 r0[4], r1[4];
#pragma unroll
        for (int c4 = 0; c4 < 4; ++c4) {
            const int c = hf * 4 + c4;
            r0[c4] = *(const float4*)(fbase + (size_t)(c * 32 + kk) * HW + pstage);
            r1[c4] = *(const float4*)(fbase + (size_t)(c * 32 + kk + 1) * HW + pstage);
        }
#pragma unroll
        for (int c4 = 0; c4 < 4; ++c4) {
            const int c = hf * 4 + c4;
            const float a0[4] = {r0[c4].x, r0[c4].y, r0[c4].z, r0[c4].w};
            const float a1[4] = {r1[c4].x, r1[c4].y, r1[c4].z, r1[c4].w};
#pragma unroll
            for (int e = 0; e < 4; ++e) {
                const int p     = pstage + e;
                const int lane2 = gS * 32 + (p & 31);
                const int pt    = p >> 5;
                const int frag  = c * 256 + (ksS * 2 + pt) * 64 + lane2;
                *(unsigned int*)&featAll[FOFF(frag) + j0h] = pkh(a0[e], a1[e]);
            }
        }
    }
    __syncthreads();

    // ---- conv1: wave w -> hidden rows [64w,64w+64), 2x2 32x32x16 accums ----
    f32x16 facc[2][2];
#pragma unroll
    for (int ot = 0; ot < 2; ++ot)
#pragma unroll
        for (int pt = 0; pt < 2; ++pt)
#pragma unroll
            for (int e = 0; e < 16; ++e) facc[ot][pt][e] = 0.f;

    half8 afb[2][2][2];
#pragma unroll
    for (int ks = 0; ks < 2; ++ks)
#pragma unroll
        for (int ot = 0; ot < 2; ++ot)
            afb[0][ks][ot] = *(const half8*)(w1s + ((size_t)((w * 2 + ot) * 16 + ks) * 64 + lane) * 8);

#pragma unroll
    for (int c = 0; c < 8; ++c) {
        if (c < 7) {
#pragma unroll
            for (int ks = 0; ks < 2; ++ks)
#pragma unroll
                for (int ot = 0; ot < 2; ++ot)
                    afb[(c + 1) & 1][ks][ot] =
                        *(const half8*)(w1s + ((size_t)((w * 2 + ot) * 16 + (c + 1) * 2 + ks) * 64 + lane) * 8);
        }
#pragma unroll
        for (int ks = 0; ks < 2; ++ks) {
#pragma unroll
            for (int pt = 0; pt < 2; ++pt) {
                const half8 bf = *(const half8*)&featAll[FOFF(c * 256 + (ks * 2 + pt) * 64 + lane)];
                facc[0][pt] = __builtin_amdgcn_mfma_f32_32x32x16_f16(afb[c & 1][ks][0], bf, facc[0][pt], 0, 0, 0);
                facc[1][pt] = __builtin_amdgcn_mfma_f32_32x32x16_f16(afb[c & 1][ks][1], bf, facc[1][pt], 0, 0, 0);
            }
        }
    }
    __syncthreads();

    // ---- bias + leaky relu, repack to conv2 B-fragment order ----
    const int col = lane & 31;
#pragma unroll
    for (int ot = 0; ot < 2; ++ot) {
        const int ks2 = w * 2 + ot;
#pragma unroll
        for (int pt = 0; pt < 2; ++pt) {
            const int pt2 = pt * 2 + (col >> 4);
            const int n15 = col & 15;
#pragma unroll
            for (int q = 0; q < 4; ++q) {
                float hv[4];
#pragma unroll
                for (int i = 0; i < 4; ++i) {
                    const int row = i + 8 * q + 4 * ghalf;
                    float v = facc[ot][pt][q * 4 + i] + bias_s[w * 64 + ot * 32 + row];
                    hv[i] = v < 0.f ? 0.01f * v : v;
                }
                const int frag = (ks2 * 4 + pt2) * 64 + (q * 16 + n15);
                *(unsigned int*)&hidf[FOFF(frag) + 4 * ghalf]     = pkh(hv[0], hv[1]);
                *(unsigned int*)&hidf[FOFF(frag) + 4 * ghalf + 2] = pkh(hv[2], hv[3]);
            }
        }
    }
    __syncthreads();

    // ---- conv2 via 16x16x32 MFMA; wave w owns pixels [16w,16w+16) ----
    f32x4 c2[5];
#pragma unroll
    for (int rt = 0; rt < 5; ++rt)
#pragma unroll
        for (int e = 0; e < 4; ++e) c2[rt][e] = 0.f;

    const int m16 = lane & 15;
    const int kgr = lane >> 4;

    half8 afc[2][5];
#pragma unroll
    for (int rt = 0; rt < 5; ++rt)
        afc[0][rt] = *(const half8*)(w2s + ((size_t)(rt * 8) * 64 + lane) * 8);

#pragma unroll
    for (int ks2 = 0; ks2 < 8; ++ks2) {
        if (ks2 < 7) {
#pragma unroll
            for (int rt = 0; rt < 5; ++rt)
                afc[(ks2 + 1) & 1][rt] =
                    *(const half8*)(w2s + ((size_t)(rt * 8 + ks2 + 1) * 64 + lane) * 8);
        }
        const half8 bf = *(const half8*)&hidf[FOFF((ks2 * 4 + w) * 64 + lane)];
#pragma unroll
        for (int rt = 0; rt < 5; ++rt)
            c2[rt] = __builtin_amdgcn_mfma_f32_16x16x32_f16(afc[ks2 & 1][rt], bf, c2[rt], 0, 0, 0);
    }
    __syncthreads();   // all hidf reads done; alias LDS as x2t + WP

    // ---- write x2 tile (wave-local rows) ----
    const int pxl = w * 16 + m16;
#pragma unroll
    for (int rt = 0; rt < 5; ++rt) {
#pragma unroll
        for (int r = 0; r < 4; ++r) {
            const int o2 = rt * 16 + kgr * 4 + r;
            if (o2 < OC) x2t[pxl * 69 + o2] = c2[rt][r] + b2[o2];
        }
    }
    asm volatile("" ::: "memory");   // same-wave DS order: x2 writes before reads

    // ---- proposals for THIS wave's 16 pixels x 9 anchors (wave-local) ----
    for (int i = lane; i < A_ * 16; i += 64) {
        const int a  = i >> 4;
        const int pw = i & 15;
        const float* xr = x2t + (w * 16 + pw) * 69 + 5 * a;
        const float tx = xr[1], ty = xr[2], tw = xr[3], th = xr[4];
        const int hwg = p0 + w * 16 + pw;
        const int h   = hwg / W_;
        const int wv  = hwg - h * W_;
        const float gx = (float)wv + 0.5f;
        const float gy = (float)h + 0.5f;
        const float nw = anc[2 * a]     * __expf(tw);
        const float nh = anc[2 * a + 1] * __expf(th);
        const float cx = gx + tx, cy = gy + ty;
        WPw[i]       = cx - 0.5f * nw;
        WPw[144 + i] = cy - 0.5f * nh;
        WPw[288 + i] = cx + 0.5f * nw;
        WPw[432 + i] = cy + 0.5f * nh;
        WPw[576 + i] = nw * nh;
    }
    asm volatile("" ::: "memory");   // WP writes before WP reads (same wave)

    // ---- IoU stream-out: wave-private, batched LDS reads per anchor ----
    const int pr = lane >> 4;
    const int j0 = (lane & 15) * 4;
    float Bx1[4], By1[4], Bx2[4], By2[4], Ba[4];
#pragma unroll
    for (int e = 0; e < 4; ++e) {
        Bx1[e] = boxs[j0 + e];       By1[e] = boxs[64 + j0 + e];
        Bx2[e] = boxs[128 + j0 + e]; By2[e] = boxs[192 + j0 + e];
        Ba[e]  = boxs[256 + j0 + e];
    }
    float* ibase = iou_out + ((size_t)b * AHW + p0) * 64;
#pragma unroll 1
    for (int a = 0; a < A_; ++a) {
        float Px1[4], Py1[4], Px2[4], Py2[4], Pa[4];
#pragma unroll
        for (int q = 0; q < 4; ++q) {
            const int idx = a * 16 + q * 4 + pr;
            Px1[q] = WPw[idx];       Py1[q] = WPw[144 + idx];
            Px2[q] = WPw[288 + idx]; Py2[q] = WPw[432 + idx];
            Pa[q]  = WPw[576 + idx];
        }
#pragma unroll
        for (int q = 0; q < 4; ++q) {
            f32x4 o4;
#pragma unroll
            for (int e = 0; e < 4; ++e) {
                const float iw = fminf(Px2[q], Bx2[e]) - fmaxf(Px1[q], Bx1[e]);
                const float ih = fminf(Py2[q], By2[e]) - fmaxf(Py1[q], By1[e]);
                const float inter = fmaxf(iw, 0.f) * fmaxf(ih, 0.f);
                o4[e] = inter * __builtin_amdgcn_rcpf(Ba[e] + Pa[q] - inter);
            }
            *(f32x4*)(ibase + ((size_t)(a * HW) + w * 16 + q * 4 + pr) * 64 + j0) = o4;
        }
    }

    // ---- scans need the whole 64-px tile: barrier, then merged pos/neg ----
    __syncthreads();

    float csum = 0.f, rsum = 0.f;
    for (int m = t; m < M_; m += 256) {
        const int ip = pos_idx[m];
        const int in_ = neg_idx[m];
        {
            const int bi  = ip / AHW;
            const int rr  = ip - bi * AHW;
            const int a   = rr / HW;
            const int px  = (rr - a * HW) - p0;
            if (bi == b && px >= 0 && px < 64) {
                const float* xr = x2t + px * 69;
                const float s = 1.f / (1.f + __expf(-xr[5 * a]));
                csum += (s - 1.f) * (s - 1.f);
#pragma unroll
                for (int k = 0; k < 4; ++k) {
                    const float d = xr[5 * a + 1 + k] - gt_off[m * 4 + k];
                    rsum += d * d;
                }
                float* co = cls_out + (size_t)m * CNUM;
#pragma unroll
                for (int c = 0; c < CNUM; ++c) co[c] = xr[45 + c];
            }
        }
        {
            const int bi  = in_ / AHW;
            const int rr  = in_ - bi * AHW;
            const int a   = rr / HW;
            const int px  = (rr - a * HW) - p0;
            if (bi == b && px >= 0 && px < 64) {
                const float s = 1.f / (1.f + __expf(-x2t[px * 69 + 5 * a]));
                csum += s * s;
            }
        }
    }
#pragma unroll
    for (int off = 32; off > 0; off >>= 1) {
        csum += __shfl_down(csum, off, 64);
        rsum += __shfl_down(rsum, off, 64);
    }
    if (lane == 0) { red[w] = csum; red[4 + w] = rsum; }
    __syncthreads();
    if (t == 0) {
        const float c  = red[0] + red[1] + red[2] + red[3];
        const float rg = red[4] + red[5] + red[6] + red[7];
        if (c != 0.f || rg != 0.f) {
            atomicAdd(&loss_ws[0], c);
            atomicAdd(&loss_ws[1], rg);
        }
    }
}

__global__ void finalize_kernel(const float* __restrict__ loss_ws, float* __restrict__ out0)
{
    out0[0] = loss_ws[0] / (2.f * (float)M_) + loss_ws[1] / (float)M_;
}

extern "C" void kernel_launch(void* const* d_in, const int* in_sizes, int n_in,
                              void* d_out, int out_size, void* d_ws, size_t ws_size,
                              hipStream_t stream) {
    (void)in_sizes; (void)n_in; (void)out_size; (void)ws_size;
    const float* features = (const float*)d_in[0];
    const float* w1       = (const float*)d_in[1];
    const float* b1       = (const float*)d_in[2];
    const float* w2       = (const float*)d_in[3];
    const float* b2       = (const float*)d_in[4];
    const float* anc      = (const float*)d_in[5];
    const float* bboxes   = (const float*)d_in[7];
    const float* gt_off   = (const float*)d_in[8];
    const int*   pos_idx  = (const int*)d_in[9];
    const int*   neg_idx  = (const int*)d_in[10];
    float* out = (float*)d_out;

    char* wsb = (char*)d_ws;
    _Float16* w1s  = (_Float16*)wsb;                 // 131,072 B
    _Float16* w2s  = w1s + 65536;                    // 40,960 B
    float* loss_ws = (float*)(wsb + 131072 + 40960); // 8 B

    prep_kernel<<<256, 256, 0, stream>>>(w1, w2, w1s, w2s, loss_ws);
    conv_iou_kernel<<<B_ * NTILE, 256, 0, stream>>>(features, w1s, b1, w2s, b2,
                                                    anc, bboxes, pos_idx, neg_idx,
                                                    gt_off, out + 1,
                                                    out + 1 + IOU_N, loss_ws);
    finalize_kernel<<<1, 1, 0, stream>>>(loss_ws, out);
}